// Round 3
// baseline (189.124 us; speedup 1.0000x reference)
//
#include <hip/hip_runtime.h>

// B=D=H=512. Inputs fp32: x, W1, b1, W2, b2, w3, b3.
// d_out = out[512] ++ gram[512,512] (fp32).
// G = 1 + H2H2^T + (1+H1H1^T)⊙(G2G2^T) + (1+XX^T)⊙(G1G1^T)
//   g2 = w3⊙1{z2>0};  g1 = (W2 g2)⊙1{z1>0}
// R3 structure: 3 launches (was 5).
//   prep      -> weight transposes/splits + x split + out init (unchanged)
//   rowchain  -> fwd1+fwd2+g1 fused: each block owns 16 sample rows x all
//                512 cols; H1(hi/lo), H2, G2 staged in LDS (64KB, XOR-swizzled
//                byte^=(row&7)<<4 to kill the 1024B-row-stride bank conflict);
//                only gram inputs written to global via coalesced 16B copies.
//   gramk     -> 5 fused bf16 syrks, split-K x4 (unchanged from R2)
// Rationale: R2 showed per-kernel time is not dominant (all <42us); the
// remaining levers are launch-chain depth and intermediate global round-trips.

#define NN 512

typedef __attribute__((ext_vector_type(8))) short v8s;
typedef __attribute__((ext_vector_type(4))) float v4f;

static __device__ __forceinline__ unsigned short f2bf(float f) {
    union { float f; unsigned u; } v; v.f = f;
    unsigned r = v.u + 0x7FFF + ((v.u >> 16) & 1);
    return (unsigned short)(r >> 16);
}
static __device__ __forceinline__ float bf2f(unsigned short h) {
    union { unsigned u; float f; } v; v.u = ((unsigned)h) << 16;
    return v.f;
}

#define MFMA(a, b, c) __builtin_amdgcn_mfma_f32_16x16x32_bf16(a, b, c, 0, 0, 0)

// ---- prep: z=0: W1 transpose+split; z=1: W2 transpose+split + plain W2b;
//            z=2: x straight split + out[i]=b3 ------------------------------
__global__ __launch_bounds__(256) void prep(
    const float* __restrict__ x, const float* __restrict__ W1,
    const float* __restrict__ W2, const float* __restrict__ b3,
    unsigned short* __restrict__ xhi, unsigned short* __restrict__ xlo,
    unsigned short* __restrict__ W1th, unsigned short* __restrict__ W1tl,
    unsigned short* __restrict__ W2th, unsigned short* __restrict__ W2tl,
    unsigned short* __restrict__ W2b, float* __restrict__ out) {
    __shared__ float T[32][33];
    const int t = threadIdx.x;
    const int lr = t >> 3, lc = (t & 7) * 4;
    const int r0 = blockIdx.y * 32, c0 = blockIdx.x * 32;
    const int z = blockIdx.z;
    if (z == 2) {
        float4 v = *(const float4*)&x[(r0 + lr) * NN + c0 + lc];
        ushort4 hi, lo;
        hi.x = f2bf(v.x); lo.x = f2bf(v.x - bf2f(hi.x));
        hi.y = f2bf(v.y); lo.y = f2bf(v.y - bf2f(hi.y));
        hi.z = f2bf(v.z); lo.z = f2bf(v.z - bf2f(hi.z));
        hi.w = f2bf(v.w); lo.w = f2bf(v.w - bf2f(hi.w));
        *(ushort4*)&xhi[(r0 + lr) * NN + c0 + lc] = hi;
        *(ushort4*)&xlo[(r0 + lr) * NN + c0 + lc] = lo;
        if (blockIdx.x == 0 && t < 32) out[r0 + t] = b3[0];
        return;
    }
    const float* src = (z == 1) ? W2 : W1;
    float4 v = *(const float4*)&src[(r0 + lr) * NN + c0 + lc];
    if (z == 1) {
        ushort4 h;
        h.x = f2bf(v.x); h.y = f2bf(v.y); h.z = f2bf(v.z); h.w = f2bf(v.w);
        *(ushort4*)&W2b[(r0 + lr) * NN + c0 + lc] = h;
    }
    T[lr][lc + 0] = v.x; T[lr][lc + 1] = v.y;
    T[lr][lc + 2] = v.z; T[lr][lc + 3] = v.w;
    __syncthreads();
    unsigned short* dh = (z == 1) ? W2th : W1th;
    unsigned short* dl = (z == 1) ? W2tl : W1tl;
    float a0 = T[lc + 0][lr], a1 = T[lc + 1][lr];
    float a2 = T[lc + 2][lr], a3 = T[lc + 3][lr];
    ushort4 hi, lo;
    hi.x = f2bf(a0); lo.x = f2bf(a0 - bf2f(hi.x));
    hi.y = f2bf(a1); lo.y = f2bf(a1 - bf2f(hi.y));
    hi.z = f2bf(a2); lo.z = f2bf(a2 - bf2f(hi.z));
    hi.w = f2bf(a3); lo.w = f2bf(a3 - bf2f(hi.w));
    *(ushort4*)&dh[(c0 + lr) * NN + r0 + lc] = hi;
    *(ushort4*)&dl[(c0 + lr) * NN + r0 + lc] = lo;
}

// ---- rowchain: fwd1 + fwd2 + g1 fused, 16 rows/block, 16 waves -----------
// wave w owns output cols [32w, 32w+32); A-fragments row-local in LDS.
__global__ __launch_bounds__(1024, 1) void rowchain(
    const unsigned short* __restrict__ xhi, const unsigned short* __restrict__ xlo,
    const unsigned short* __restrict__ W1th, const unsigned short* __restrict__ W1tl,
    const unsigned short* __restrict__ W2th, const unsigned short* __restrict__ W2tl,
    const unsigned short* __restrict__ W2b,
    const float* __restrict__ b1, const float* __restrict__ b2,
    const float* __restrict__ w3,
    unsigned short* __restrict__ H1b, unsigned short* __restrict__ H2b,
    unsigned short* __restrict__ G2b, unsigned short* __restrict__ G1b,
    float* __restrict__ out) {
    __shared__ unsigned short Hhi[16][512];
    __shared__ unsigned short Hlo[16][512];   // reused as G1 staging in phase C
    __shared__ unsigned short H2s[16][512];
    __shared__ unsigned short G2s[16][512];
    const int t = threadIdx.x;
    const int wave = t >> 6, lane = t & 63;
    const int r = lane & 15, quad = lane >> 4;
    const int i0 = blockIdx.x * 16;
    const int j0 = wave * 32;
    const int ao = (i0 + r) * NN + quad * 8;

    // ---- phase A: h1 = relu(x@W1+b1), split hi/lo into LDS ----
    for (int jt = 0; jt < 32; jt += 16) {
        const int bo = (j0 + jt + r) * NN + quad * 8;
        v4f hh = {0.f, 0.f, 0.f, 0.f}, lh = hh, hl = hh;
        #pragma unroll
        for (int k0 = 0; k0 < NN; k0 += 32) {
            v8s ah = *(const v8s*)(xhi + ao + k0);
            v8s al = *(const v8s*)(xlo + ao + k0);
            v8s bh = *(const v8s*)(W1th + bo + k0);
            v8s bl = *(const v8s*)(W1tl + bo + k0);
            hh = MFMA(ah, bh, hh);
            lh = MFMA(al, bh, lh);
            hl = MFMA(ah, bl, hl);
        }
        const int j = j0 + jt + r;
        const float bj = b1[j];
        #pragma unroll
        for (int rr = 0; rr < 4; ++rr) {
            const int row = quad * 4 + rr;
            float zv = (hh[rr] + lh[rr]) + hl[rr] + bj;
            float h = zv > 0.f ? zv : 0.f;
            unsigned short hb = f2bf(h);
            const int cb = (2 * j) ^ ((row & 7) << 4);
            *(unsigned short*)((char*)Hhi + row * 1024 + cb) = hb;
            *(unsigned short*)((char*)Hlo + row * 1024 + cb) = f2bf(h - bf2f(hb));
        }
    }
    __syncthreads();
    // coop copy Hhi -> H1b (read-only on LDS, overlaps phase B scheduling)
    {
        const int row = wave;
        const int cb = (lane * 16) ^ ((row & 7) << 4);
        v8s vv = *(const v8s*)((char*)Hhi + row * 1024 + cb);
        *(v8s*)(H1b + (i0 + row) * NN + lane * 8) = vv;
    }

    // ---- phase B: z2 = h1@W2+b2 -> H2s, G2s; out += h2.w3 ----
    float psum[4] = {0.f, 0.f, 0.f, 0.f};
    for (int jt = 0; jt < 32; jt += 16) {
        const int bo = (j0 + jt + r) * NN + quad * 8;
        v4f hh = {0.f, 0.f, 0.f, 0.f}, lh = hh, hl = hh;
        #pragma unroll
        for (int k0 = 0; k0 < NN; k0 += 32) {
            const int cb = (2 * (k0 + quad * 8)) ^ ((r & 7) << 4);
            v8s ah = *(const v8s*)((char*)Hhi + r * 1024 + cb);
            v8s al = *(const v8s*)((char*)Hlo + r * 1024 + cb);
            v8s bh = *(const v8s*)(W2th + bo + k0);
            v8s bl = *(const v8s*)(W2tl + bo + k0);
            hh = MFMA(ah, bh, hh);
            lh = MFMA(al, bh, lh);
            hl = MFMA(ah, bl, hl);
        }
        const int j = j0 + jt + r;
        const float bj = b2[j];
        const float wj = w3[j];
        const unsigned short wjb = f2bf(wj);
        #pragma unroll
        for (int rr = 0; rr < 4; ++rr) {
            const int row = quad * 4 + rr;
            float zv = (hh[rr] + lh[rr]) + hl[rr] + bj;
            float h = zv > 0.f ? zv : 0.f;
            const int cb = (2 * j) ^ ((row & 7) << 4);
            *(unsigned short*)((char*)H2s + row * 1024 + cb) = f2bf(h);
            *(unsigned short*)((char*)G2s + row * 1024 + cb) =
                (zv > 0.f) ? wjb : (unsigned short)0;
            psum[rr] += h * wj;
        }
    }
    #pragma unroll
    for (int rr = 0; rr < 4; ++rr) {
        float p = psum[rr];
        p += __shfl_xor(p, 1, 64);
        p += __shfl_xor(p, 2, 64);
        p += __shfl_xor(p, 4, 64);
        p += __shfl_xor(p, 8, 64);
        if (r == 0) atomicAdd(&out[i0 + quad * 4 + rr], p);
    }
    __syncthreads();

    // ---- phase C: G1 = 1{h1>0} . (G2 @ W2^T) into Hlo (G1 staging) ----
    for (int ct = 0; ct < 32; ct += 16) {
        const int bo = (j0 + ct + r) * NN + quad * 8;
        v4f acc = {0.f, 0.f, 0.f, 0.f};
        #pragma unroll
        for (int k0 = 0; k0 < NN; k0 += 32) {
            const int cb = (2 * (k0 + quad * 8)) ^ ((r & 7) << 4);
            v8s a = *(const v8s*)((char*)G2s + r * 1024 + cb);
            v8s b = *(const v8s*)(W2b + bo + k0);
            acc = MFMA(a, b, acc);
        }
        const int c = j0 + ct + r;
        #pragma unroll
        for (int rr = 0; rr < 4; ++rr) {
            const int row = quad * 4 + rr;
            const int cb = (2 * c) ^ ((row & 7) << 4);
            // h1 >= 0, bf16(h1) != 0 iff h1 > 0 (up to denormal cutoff)
            unsigned short m = *(const unsigned short*)((char*)Hhi + row * 1024 + cb);
            float v = (m != 0) ? acc[rr] : 0.f;
            *(unsigned short*)((char*)Hlo + row * 1024 + cb) = f2bf(v);
        }
    }
    __syncthreads();
    // ---- coop copies: H2s->H2b, G2s->G2b, Hlo(G1)->G1b ----
    {
        const int row = wave;
        const int cb = (lane * 16) ^ ((row & 7) << 4);
        const int go = (i0 + row) * NN + lane * 8;
        *(v8s*)(H2b + go) = *(const v8s*)((char*)H2s + row * 1024 + cb);
        *(v8s*)(G2b + go) = *(const v8s*)((char*)G2s + row * 1024 + cb);
        *(v8s*)(G1b + go) = *(const v8s*)((char*)Hlo + row * 1024 + cb);
    }
}

// ---- gram: 5 bf16 syrks fused, split-K x4 (unchanged from R2) ------------
__global__ __launch_bounds__(1024, 4) void gramk(
    const unsigned short* __restrict__ Xb, const unsigned short* __restrict__ H1b,
    const unsigned short* __restrict__ G1b, const unsigned short* __restrict__ H2b,
    const unsigned short* __restrict__ G2b, float* __restrict__ gram) {
    __shared__ float red[12][64][5][4];
    const int t = threadIdx.x;
    const int wave = t >> 6, lane = t & 63;
    const int q = wave & 3, s = wave >> 2;
    const int r = lane & 15, quad = lane >> 4;
    const int i0 = blockIdx.y * 32 + 16 * (q >> 1);
    const int j0 = blockIdx.x * 32 + 16 * (q & 1);
    const int ao = (i0 + r) * NN + quad * 8 + s * 128;
    const int bo = (j0 + r) * NN + quad * 8 + s * 128;
    v4f a0 = {0.f, 0.f, 0.f, 0.f}, a1 = a0, a2 = a0, a3 = a0, a4 = a0;
    #pragma unroll
    for (int k0 = 0; k0 < 128; k0 += 32) {
        v8s xa = *(const v8s*)(Xb  + ao + k0), xb2 = *(const v8s*)(Xb  + bo + k0);
        v8s ha = *(const v8s*)(H1b + ao + k0), hb  = *(const v8s*)(H1b + bo + k0);
        v8s ga = *(const v8s*)(G1b + ao + k0), gb  = *(const v8s*)(G1b + bo + k0);
        v8s ua = *(const v8s*)(H2b + ao + k0), ub  = *(const v8s*)(H2b + bo + k0);
        v8s va = *(const v8s*)(G2b + ao + k0), vb  = *(const v8s*)(G2b + bo + k0);
        a0 = MFMA(xa, xb2, a0);
        a1 = MFMA(ha, hb,  a1);
        a2 = MFMA(ga, gb,  a2);
        a3 = MFMA(ua, ub,  a3);
        a4 = MFMA(va, vb,  a4);
    }
    if (s > 0) {
        const int idx = (s - 1) * 4 + q;
        *(v4f*)red[idx][lane][0] = a0;
        *(v4f*)red[idx][lane][1] = a1;
        *(v4f*)red[idx][lane][2] = a2;
        *(v4f*)red[idx][lane][3] = a3;
        *(v4f*)red[idx][lane][4] = a4;
    }
    __syncthreads();
    if (s == 0) {
        #pragma unroll
        for (int u = 0; u < 3; ++u) {
            const int idx = u * 4 + q;
            a0 += *(v4f*)red[idx][lane][0];
            a1 += *(v4f*)red[idx][lane][1];
            a2 += *(v4f*)red[idx][lane][2];
            a3 += *(v4f*)red[idx][lane][3];
            a4 += *(v4f*)red[idx][lane][4];
        }
        #pragma unroll
        for (int rr = 0; rr < 4; ++rr) {
            const int i = i0 + quad * 4 + rr;
            const int j = j0 + r;
            float g = 1.f + a3[rr] + a4[rr] * (1.f + a1[rr]) + a2[rr] * (1.f + a0[rr]);
            gram[i * NN + j] = g;
        }
    }
}

extern "C" void kernel_launch(void* const* d_in, const int* in_sizes, int n_in,
                              void* d_out, int out_size, void* d_ws, size_t ws_size,
                              hipStream_t stream) {
    const float* x  = (const float*)d_in[0];
    const float* W1 = (const float*)d_in[1];
    const float* b1 = (const float*)d_in[2];
    const float* W2 = (const float*)d_in[3];
    const float* b2 = (const float*)d_in[4];
    const float* w3 = (const float*)d_in[5];
    const float* b3 = (const float*)d_in[6];

    float* out  = (float*)d_out;
    float* gram = out + NN;

    // 11 bf16 [512][512] arrays, 512 KB each
    unsigned short* p    = (unsigned short*)d_ws;
    unsigned short* xhi  = p;  p += NN * NN;
    unsigned short* xlo  = p;  p += NN * NN;
    unsigned short* W1th = p;  p += NN * NN;
    unsigned short* W1tl = p;  p += NN * NN;
    unsigned short* W2th = p;  p += NN * NN;
    unsigned short* W2tl = p;  p += NN * NN;
    unsigned short* W2b  = p;  p += NN * NN;
    unsigned short* H1b  = p;  p += NN * NN;
    unsigned short* H2b  = p;  p += NN * NN;
    unsigned short* G2b  = p;  p += NN * NN;
    unsigned short* G1b  = p;  p += NN * NN;

    prep <<<dim3(16, 16, 3), dim3(256), 0, stream>>>(
        x, W1, W2, b3, xhi, xlo, W1th, W1tl, W2th, W2tl, W2b, out);
    rowchain<<<dim3(32), dim3(1024), 0, stream>>>(
        xhi, xlo, W1th, W1tl, W2th, W2tl, W2b, b1, b2, w3,
        H1b, H2b, G2b, G1b, out);
    gramk<<<dim3(16, 16), dim3(1024), 0, stream>>>(
        xhi, H1b, G1b, H2b, G2b, gram);
}

// Round 4
// 115.832 us; speedup vs baseline: 1.6327x; 1.6327x over previous
//
#include <hip/hip_runtime.h>

// B=D=H=512. Inputs fp32: x, W1, b1, W2, b2, w3, b3.
// d_out = out[512] ++ gram[512,512] (fp32).
// G = 1 + H2H2^T + (1+H1H1^T)⊙(G2G2^T) + (1+XX^T)⊙(G1G1^T)
//   g2 = w3⊙1{z2>0};  g1 = (W2 g2)⊙1{z1>0}
// R4: R2 base (5 launches, split-K x4, 1024-thr blocks) with syrk work
// rebalanced off the tail:
//   prep   -> unchanged
//   fwd1x  -> z=0: fwd1;  z=1: SXX = XX^T syrk (f32)        [512 blocks]
//   fwd2   -> unchanged
//   g1p    -> z=0: g1;    z=1: P = H2H2^T+G2G2^T.(1+H1H1^T) [512 blocks]
//   gramf  -> 1 syrk (G1) + read SXX,P + combine             (was 5 syrks)
// Fixed ~84us of the timed window is harness workspace re-poison
// (2x 42us fillBuffer, 256MiB each) — not addressable from the kernel.

#define NN 512

typedef __attribute__((ext_vector_type(8))) short v8s;
typedef __attribute__((ext_vector_type(4))) float v4f;

static __device__ __forceinline__ unsigned short f2bf(float f) {
    union { float f; unsigned u; } v; v.f = f;
    unsigned r = v.u + 0x7FFF + ((v.u >> 16) & 1);
    return (unsigned short)(r >> 16);
}
static __device__ __forceinline__ float bf2f(unsigned short h) {
    union { unsigned u; float f; } v; v.u = ((unsigned)h) << 16;
    return v.f;
}

#define MFMA(a, b, c) __builtin_amdgcn_mfma_f32_16x16x32_bf16(a, b, c, 0, 0, 0)

// ---- prep: z=0: W1 transpose+split; z=1: W2 transpose+split + plain W2b;
//            z=2: x straight split + out[i]=b3 ------------------------------
__global__ __launch_bounds__(256) void prep(
    const float* __restrict__ x, const float* __restrict__ W1,
    const float* __restrict__ W2, const float* __restrict__ b3,
    unsigned short* __restrict__ xhi, unsigned short* __restrict__ xlo,
    unsigned short* __restrict__ W1th, unsigned short* __restrict__ W1tl,
    unsigned short* __restrict__ W2th, unsigned short* __restrict__ W2tl,
    unsigned short* __restrict__ W2b, float* __restrict__ out) {
    __shared__ float T[32][33];
    const int t = threadIdx.x;
    const int lr = t >> 3, lc = (t & 7) * 4;
    const int r0 = blockIdx.y * 32, c0 = blockIdx.x * 32;
    const int z = blockIdx.z;
    if (z == 2) {
        float4 v = *(const float4*)&x[(r0 + lr) * NN + c0 + lc];
        ushort4 hi, lo;
        hi.x = f2bf(v.x); lo.x = f2bf(v.x - bf2f(hi.x));
        hi.y = f2bf(v.y); lo.y = f2bf(v.y - bf2f(hi.y));
        hi.z = f2bf(v.z); lo.z = f2bf(v.z - bf2f(hi.z));
        hi.w = f2bf(v.w); lo.w = f2bf(v.w - bf2f(hi.w));
        *(ushort4*)&xhi[(r0 + lr) * NN + c0 + lc] = hi;
        *(ushort4*)&xlo[(r0 + lr) * NN + c0 + lc] = lo;
        if (blockIdx.x == 0 && t < 32) out[r0 + t] = b3[0];
        return;
    }
    const float* src = (z == 1) ? W2 : W1;
    float4 v = *(const float4*)&src[(r0 + lr) * NN + c0 + lc];
    if (z == 1) {
        ushort4 h;
        h.x = f2bf(v.x); h.y = f2bf(v.y); h.z = f2bf(v.z); h.w = f2bf(v.w);
        *(ushort4*)&W2b[(r0 + lr) * NN + c0 + lc] = h;
    }
    T[lr][lc + 0] = v.x; T[lr][lc + 1] = v.y;
    T[lr][lc + 2] = v.z; T[lr][lc + 3] = v.w;
    __syncthreads();
    unsigned short* dh = (z == 1) ? W2th : W1th;
    unsigned short* dl = (z == 1) ? W2tl : W1tl;
    float a0 = T[lc + 0][lr], a1 = T[lc + 1][lr];
    float a2 = T[lc + 2][lr], a3 = T[lc + 3][lr];
    ushort4 hi, lo;
    hi.x = f2bf(a0); lo.x = f2bf(a0 - bf2f(hi.x));
    hi.y = f2bf(a1); lo.y = f2bf(a1 - bf2f(hi.y));
    hi.z = f2bf(a2); lo.z = f2bf(a2 - bf2f(hi.z));
    hi.w = f2bf(a3); lo.w = f2bf(a3 - bf2f(hi.w));
    *(ushort4*)&dh[(c0 + lr) * NN + r0 + lc] = hi;
    *(ushort4*)&dl[(c0 + lr) * NN + r0 + lc] = lo;
}

// ---- fwd1x: z=0: h1=relu(x@W1+b1) split out; z=1: SXX = x@x^T syrk -------
__global__ __launch_bounds__(1024, 4) void fwd1x(
    const unsigned short* __restrict__ Ahi, const unsigned short* __restrict__ Alo,
    const unsigned short* __restrict__ Bhi, const unsigned short* __restrict__ Blo,
    const float* __restrict__ bias,
    unsigned short* __restrict__ Chi, unsigned short* __restrict__ Clo,
    float* __restrict__ SXX) {
    __shared__ float red[12][64][4];
    const int t = threadIdx.x;
    const int wave = t >> 6, lane = t & 63;
    const int q = wave & 3, s = wave >> 2;
    const int r = lane & 15, quad = lane >> 4;
    const int i0 = blockIdx.y * 32 + 16 * (q >> 1);
    const int j0 = blockIdx.x * 32 + 16 * (q & 1);
    const int ao = (i0 + r) * NN + quad * 8 + s * 128;
    const int bo = (j0 + r) * NN + quad * 8 + s * 128;
    if (blockIdx.z == 1) {
        // XX^T syrk on hi parts (same operand precision as R2 gramk)
        v4f acc = {0.f, 0.f, 0.f, 0.f};
        #pragma unroll
        for (int k0 = 0; k0 < 128; k0 += 32) {
            v8s a = *(const v8s*)(Ahi + ao + k0);
            v8s b = *(const v8s*)(Ahi + bo + k0);
            acc = MFMA(a, b, acc);
        }
        if (s > 0) *(v4f*)red[(s - 1) * 4 + q][lane] = acc;
        __syncthreads();
        if (s == 0) {
            v4f a0 = acc + *(v4f*)red[q][lane] + *(v4f*)red[4 + q][lane]
                         + *(v4f*)red[8 + q][lane];
            #pragma unroll
            for (int rr = 0; rr < 4; ++rr)
                SXX[(i0 + quad * 4 + rr) * NN + j0 + r] = a0[rr];
        }
        return;
    }
    v4f hh = {0.f, 0.f, 0.f, 0.f}, lh = hh, hl = hh;
    #pragma unroll
    for (int k0 = 0; k0 < 128; k0 += 32) {
        v8s ah = *(const v8s*)(Ahi + ao + k0);
        v8s al = *(const v8s*)(Alo + ao + k0);
        v8s bh = *(const v8s*)(Bhi + bo + k0);
        v8s bl = *(const v8s*)(Blo + bo + k0);
        hh = MFMA(ah, bh, hh);
        lh = MFMA(al, bh, lh);
        hl = MFMA(ah, bl, hl);
    }
    v4f z;
    #pragma unroll
    for (int rr = 0; rr < 4; ++rr) z[rr] = (hh[rr] + lh[rr]) + hl[rr];
    if (s > 0) *(v4f*)red[(s - 1) * 4 + q][lane] = z;
    __syncthreads();
    if (s == 0) {
        v4f z0 = z + *(v4f*)red[q][lane] + *(v4f*)red[4 + q][lane]
                   + *(v4f*)red[8 + q][lane];
        const float bj = bias[j0 + r];
        #pragma unroll
        for (int rr = 0; rr < 4; ++rr) {
            const int i = i0 + quad * 4 + rr, j = j0 + r;
            float zv = z0[rr] + bj;
            float h = zv > 0.f ? zv : 0.f;
            unsigned short hi = f2bf(h);
            Chi[i * NN + j] = hi;
            Clo[i * NN + j] = f2bf(h - bf2f(hi));
        }
    }
}

// ---- fwd2: z2 = H1@W2+b2; writes H2b, G2b, out += h2.w3 (R2, unchanged) --
__global__ __launch_bounds__(1024, 4) void fwd2(
    const unsigned short* __restrict__ Ahi, const unsigned short* __restrict__ Alo,
    const unsigned short* __restrict__ Bhi, const unsigned short* __restrict__ Blo,
    const float* __restrict__ b2, const float* __restrict__ w3,
    unsigned short* __restrict__ H2b, unsigned short* __restrict__ G2b,
    float* __restrict__ out) {
    __shared__ float red[12][64][4];
    const int t = threadIdx.x;
    const int wave = t >> 6, lane = t & 63;
    const int q = wave & 3, s = wave >> 2;
    const int r = lane & 15, quad = lane >> 4;
    const int i0 = blockIdx.y * 32 + 16 * (q >> 1);
    const int j0 = blockIdx.x * 32 + 16 * (q & 1);
    const int ao = (i0 + r) * NN + quad * 8 + s * 128;
    const int bo = (j0 + r) * NN + quad * 8 + s * 128;
    v4f hh = {0.f, 0.f, 0.f, 0.f}, lh = hh, hl = hh;
    #pragma unroll
    for (int k0 = 0; k0 < 128; k0 += 32) {
        v8s ah = *(const v8s*)(Ahi + ao + k0);
        v8s al = *(const v8s*)(Alo + ao + k0);
        v8s bh = *(const v8s*)(Bhi + bo + k0);
        v8s bl = *(const v8s*)(Blo + bo + k0);
        hh = MFMA(ah, bh, hh);
        lh = MFMA(al, bh, lh);
        hl = MFMA(ah, bl, hl);
    }
    v4f z;
    #pragma unroll
    for (int rr = 0; rr < 4; ++rr) z[rr] = (hh[rr] + lh[rr]) + hl[rr];
    if (s > 0) *(v4f*)red[(s - 1) * 4 + q][lane] = z;
    __syncthreads();
    if (s == 0) {
        v4f z0 = z + *(v4f*)red[q][lane] + *(v4f*)red[4 + q][lane]
                   + *(v4f*)red[8 + q][lane];
        const float bj = b2[j0 + r];
        const float wj = w3[j0 + r];
        const unsigned short wjb = f2bf(wj);
        #pragma unroll
        for (int rr = 0; rr < 4; ++rr) {
            const int i = i0 + quad * 4 + rr, j = j0 + r;
            float zv = z0[rr] + bj;
            float h = zv > 0.f ? zv : 0.f;
            H2b[i * NN + j] = f2bf(h);
            G2b[i * NN + j] = (zv > 0.f) ? wjb : (unsigned short)0;
            float p = h * wj;
            p += __shfl_xor(p, 1, 64);
            p += __shfl_xor(p, 2, 64);
            p += __shfl_xor(p, 4, 64);
            p += __shfl_xor(p, 8, 64);
            if (r == 0) atomicAdd(&out[i], p);
        }
    }
}

// ---- g1p: z=0: G1 = 1{H1>0}.(G2@W2^T); z=1: P = H2H2+G2G2.(1+H1H1) ------
__global__ __launch_bounds__(1024, 4) void g1p(
    const unsigned short* __restrict__ G2b, const unsigned short* __restrict__ W2b,
    const unsigned short* __restrict__ H1b, const unsigned short* __restrict__ H2b,
    unsigned short* __restrict__ G1b, float* __restrict__ P) {
    __shared__ float red[12][64][3][4];
    const int t = threadIdx.x;
    const int wave = t >> 6, lane = t & 63;
    const int q = wave & 3, s = wave >> 2;
    const int r = lane & 15, quad = lane >> 4;
    const int i0 = blockIdx.y * 32 + 16 * (q >> 1);
    const int j0 = blockIdx.x * 32 + 16 * (q & 1);
    const int ao = (i0 + r) * NN + quad * 8 + s * 128;
    const int bo = (j0 + r) * NN + quad * 8 + s * 128;
    if (blockIdx.z == 1) {
        v4f a1 = {0.f, 0.f, 0.f, 0.f}, a3 = a1, a4 = a1;
        #pragma unroll
        for (int k0 = 0; k0 < 128; k0 += 32) {
            v8s ha = *(const v8s*)(H1b + ao + k0), hb = *(const v8s*)(H1b + bo + k0);
            v8s ua = *(const v8s*)(H2b + ao + k0), ub = *(const v8s*)(H2b + bo + k0);
            v8s va = *(const v8s*)(G2b + ao + k0), vb = *(const v8s*)(G2b + bo + k0);
            a1 = MFMA(ha, hb, a1);
            a3 = MFMA(ua, ub, a3);
            a4 = MFMA(va, vb, a4);
        }
        if (s > 0) {
            const int idx = (s - 1) * 4 + q;
            *(v4f*)red[idx][lane][0] = a1;
            *(v4f*)red[idx][lane][1] = a3;
            *(v4f*)red[idx][lane][2] = a4;
        }
        __syncthreads();
        if (s == 0) {
            #pragma unroll
            for (int u = 0; u < 3; ++u) {
                const int idx = u * 4 + q;
                a1 += *(v4f*)red[idx][lane][0];
                a3 += *(v4f*)red[idx][lane][1];
                a4 += *(v4f*)red[idx][lane][2];
            }
            #pragma unroll
            for (int rr = 0; rr < 4; ++rr) {
                const int i = i0 + quad * 4 + rr, j = j0 + r;
                P[i * NN + j] = a3[rr] + a4[rr] * (1.f + a1[rr]);
            }
        }
        return;
    }
    v4f acc = {0.f, 0.f, 0.f, 0.f};
    #pragma unroll
    for (int k0 = 0; k0 < 128; k0 += 32) {
        v8s a = *(const v8s*)(G2b + ao + k0);
        v8s b = *(const v8s*)(W2b + bo + k0);
        acc = MFMA(a, b, acc);
    }
    if (s > 0) *(v4f*)red[(s - 1) * 4 + q][lane][0] = acc;
    __syncthreads();
    if (s == 0) {
        v4f a0 = acc + *(v4f*)red[q][lane][0] + *(v4f*)red[4 + q][lane][0]
                     + *(v4f*)red[8 + q][lane][0];
        #pragma unroll
        for (int rr = 0; rr < 4; ++rr) {
            const int i = i0 + quad * 4 + rr;
            const int c = j0 + r;
            // h1 >= 0, bf16(h1) != 0 iff h1 > 0 (up to denormal cutoff)
            float v = (H1b[i * NN + c] != 0) ? a0[rr] : 0.f;
            G1b[i * NN + c] = f2bf(v);
        }
    }
}

// ---- gramf: G1 syrk + combine with precomputed SXX, P --------------------
__global__ __launch_bounds__(1024, 4) void gramf(
    const unsigned short* __restrict__ G1b, const float* __restrict__ SXX,
    const float* __restrict__ P, float* __restrict__ gram) {
    __shared__ float red[12][64][4];
    const int t = threadIdx.x;
    const int wave = t >> 6, lane = t & 63;
    const int q = wave & 3, s = wave >> 2;
    const int r = lane & 15, quad = lane >> 4;
    const int i0 = blockIdx.y * 32 + 16 * (q >> 1);
    const int j0 = blockIdx.x * 32 + 16 * (q & 1);
    const int ao = (i0 + r) * NN + quad * 8 + s * 128;
    const int bo = (j0 + r) * NN + quad * 8 + s * 128;
    v4f acc = {0.f, 0.f, 0.f, 0.f};
    #pragma unroll
    for (int k0 = 0; k0 < 128; k0 += 32) {
        v8s a = *(const v8s*)(G1b + ao + k0);
        v8s b = *(const v8s*)(G1b + bo + k0);
        acc = MFMA(a, b, acc);
    }
    if (s > 0) *(v4f*)red[(s - 1) * 4 + q][lane] = acc;
    __syncthreads();
    if (s == 0) {
        v4f a2 = acc + *(v4f*)red[q][lane] + *(v4f*)red[4 + q][lane]
                     + *(v4f*)red[8 + q][lane];
        #pragma unroll
        for (int rr = 0; rr < 4; ++rr) {
            const int i = i0 + quad * 4 + rr, j = j0 + r;
            gram[i * NN + j] = 1.f + P[i * NN + j] + a2[rr] * (1.f + SXX[i * NN + j]);
        }
    }
}

extern "C" void kernel_launch(void* const* d_in, const int* in_sizes, int n_in,
                              void* d_out, int out_size, void* d_ws, size_t ws_size,
                              hipStream_t stream) {
    const float* x  = (const float*)d_in[0];
    const float* W1 = (const float*)d_in[1];
    const float* b1 = (const float*)d_in[2];
    const float* W2 = (const float*)d_in[3];
    const float* b2 = (const float*)d_in[4];
    const float* w3 = (const float*)d_in[5];
    const float* b3 = (const float*)d_in[6];

    float* out  = (float*)d_out;
    float* gram = out + NN;

    // bf16 [512][512] arrays (512 KB each) + 2 fp32 [512][512] (1 MB each)
    unsigned short* p    = (unsigned short*)d_ws;
    unsigned short* xhi  = p;  p += NN * NN;
    unsigned short* xlo  = p;  p += NN * NN;
    unsigned short* W1th = p;  p += NN * NN;
    unsigned short* W1tl = p;  p += NN * NN;
    unsigned short* W2th = p;  p += NN * NN;
    unsigned short* W2tl = p;  p += NN * NN;
    unsigned short* W2b  = p;  p += NN * NN;
    unsigned short* H1b  = p;  p += NN * NN;
    unsigned short* H1lo = p;  p += NN * NN;
    unsigned short* H2b  = p;  p += NN * NN;
    unsigned short* G2b  = p;  p += NN * NN;
    unsigned short* G1b  = p;  p += NN * NN;
    float* SXX = (float*)p;  p += 2 * NN * NN;
    float* Pf  = (float*)p;  p += 2 * NN * NN;

    prep <<<dim3(16, 16, 3), dim3(256), 0, stream>>>(
        x, W1, W2, b3, xhi, xlo, W1th, W1tl, W2th, W2tl, W2b, out);
    fwd1x<<<dim3(16, 16, 2), dim3(1024), 0, stream>>>(
        xhi, xlo, W1th, W1tl, b1, H1b, H1lo, SXX);
    fwd2 <<<dim3(16, 16), dim3(1024), 0, stream>>>(
        H1b, H1lo, W2th, W2tl, b2, w3, H2b, G2b, out);
    g1p  <<<dim3(16, 16, 2), dim3(1024), 0, stream>>>(
        G2b, W2b, H1b, H2b, G1b, Pf);
    gramf<<<dim3(16, 16), dim3(1024), 0, stream>>>(
        G1b, SXX, Pf, gram);
}